// Round 1
// 266.681 us; speedup vs baseline: 1.0445x; 1.0445x over previous
//
#include <hip/hip_runtime.h>
#include <hip/hip_bf16.h>
#include <cstdint>

using bf16 = __hip_bfloat16;
typedef __attribute__((ext_vector_type(8))) short short8;
typedef __attribute__((ext_vector_type(4))) float floatx4;

// Problem constants
static constexpr int BATCH = 8192;
static constexpr int K1    = 2304;   // OBS + NH
static constexpr int N1    = 2048;   // NH
static constexpr int K2    = 2048;   // NH
static constexpr int N2    = 256;    // 2*LAT
static constexpr int KT1   = K1 / 64;  // 36 K-tiles of 64

__device__ __forceinline__ void gload_lds16(const void* g, void* l) {
  __builtin_amdgcn_global_load_lds(
      (const __attribute__((address_space(1))) void*)g,
      (__attribute__((address_space(3))) void*)l, 16, 0, 0);
}

// tanh(x) = 1 - 2/(1+e^{2x}); exp2-based, saturates to +/-1, err ~1e-6
__device__ __forceinline__ float fast_tanh(float x) {
  float e = __builtin_amdgcn_exp2f(x * 2.8853900817779268f);  // 2*log2(e)
  return 1.0f - 2.0f * __builtin_amdgcn_rcpf(e + 1.0f);
}

__device__ __forceinline__ short8 cvt8(const float* src) {
  float4 a = ((const float4*)src)[0];
  float4 b = ((const float4*)src)[1];
  union { short8 v; bf16 e[8]; } u;
  u.e[0] = __float2bfloat16(a.x); u.e[1] = __float2bfloat16(a.y);
  u.e[2] = __float2bfloat16(a.z); u.e[3] = __float2bfloat16(a.w);
  u.e[4] = __float2bfloat16(b.x); u.e[5] = __float2bfloat16(b.y);
  u.e[6] = __float2bfloat16(b.z); u.e[7] = __float2bfloat16(b.w);
  return u.v;
}

// ---------------- fused prep: cat(x,h)->bf16, W_i2h->bf16, W_h2o->bf16 ----
static constexpr int SEG0 = BATCH * (K1 / 8);          // 2,359,296
static constexpr int SEG1 = N1 * K1 / 8;               //   589,824
static constexpr int SEG2 = N2 * K2 / 8;               //    65,536
__global__ __launch_bounds__(256) void prep(
    const float* __restrict__ x, const float* __restrict__ h,
    const float* __restrict__ W1, const float* __restrict__ W2,
    bf16* __restrict__ comb, bf16* __restrict__ W1b, bf16* __restrict__ W2b) {
  int i = blockIdx.x * 256 + threadIdx.x;
  if (i < SEG0) {
    int row  = i / 288;
    int slot = i - row * 288;
    const float* src = (slot < 32) ? (x + (size_t)row * 256 + slot * 8)
                                   : (h + (size_t)row * 2048 + (slot - 32) * 8);
    *(short8*)(comb + (size_t)row * 2304 + slot * 8) = cvt8(src);
  } else if (i < SEG0 + SEG1) {
    int j = i - SEG0;
    *(short8*)(W1b + (size_t)j * 8) = cvt8(W1 + (size_t)j * 8);
  } else {
    int j = i - (SEG0 + SEG1);
    *(short8*)(W2b + (size_t)j * 8) = cvt8(W2 + (size_t)j * 8);
  }
}

// out = bias broadcast (seed for gemm2's split-K atomic accumulation)
__global__ __launch_bounds__(256) void bias_init(
    const float* __restrict__ bias, float* __restrict__ out) {
  int i = blockIdx.x * 256 + threadIdx.x;   // BATCH*64 threads, float4 each
  float4 b = ((const float4*)bias)[i & 63];
  ((float4*)out)[i] = b;
}

// ---------------- GEMM1: h_new = tanh(A @ W^T + bias) ----------------
// 256x256 tile, BK=64, 8 waves (2M x 4N), 128x64 per wave, 16x16x32 MFMA.
// 8-phase schedule: per phase {8 ds_read_b128 + stage 1 half-tile} ->
// s_barrier -> lgkmcnt(0) -> setprio(1) -> 16 MFMA -> setprio(0) -> s_barrier.
// Counted vmcnt(4) only at phases 4 and 8 (never 0 in the main loop).
// LDS [buf][A/B][khalf][256*32]: K-half-major so staging destinations are
// linear for global_load_lds and half-tiles retire independently.
//
// Stage schedule (iteration t, n = 2t; buf0 holds even K-tiles):
//   p0: buf1.A.kh1 <- n+1   p1: buf1.B.kh1 <- n+1
//   p2: buf0.A.kh0 <- n+2   p3: buf0.B.kh0 <- n+2  [vmcnt(4)]
//   p4: buf0.A.kh1 <- n+2   p5: buf0.B.kh1 <- n+2
//   p6: buf1.A.kh0 <- n+3   p7: buf1.B.kh0 <- n+3  [vmcnt(4)]
// Every stage targets a region whose last reader finished >=1 barrier earlier;
// vmcnt(4) at p3 covers {prev p6,p7, p0,p1}; at p7 covers {p2..p5}.
__global__ __launch_bounds__(512, 2) void gemm1_tanh(
    const bf16* __restrict__ A, const bf16* __restrict__ W,
    const float* __restrict__ bias,
    float* __restrict__ hf32, bf16* __restrict__ hb16) {
  __shared__ bf16 lds[2][2][2][8192];   // 128 KiB total
  const int t    = threadIdx.x;         // 0..511
  const int lane = t & 63;
  const int wave = t >> 6;              // 0..7
  const int wm   = (wave >> 2) * 128;   // 0 or 128
  const int wn   = (wave & 3) * 64;     // 0,64,128,192
  const int quad = lane >> 4;
  const int r15  = lane & 15;

  // staging: thread covers row r = j*128 + (t>>2), 16B slot s = t&3,
  // pre-swizzled global col so LDS dest stays linear (dest = j*8192 + t*16).
  const int srow  = t >> 2;             // 0..127
  const int sslot = t & 3;
  const int sq    = (sslot ^ (srow & 3)) * 8;   // element offset within K-half

  const size_t Abase = (size_t)blockIdx.x * 256 * K1;
  const size_t Bbase = (size_t)blockIdx.y * 256 * K1;
  const size_t gA0 = Abase + (size_t)srow * K1 + sq;
  const size_t gA1 = Abase + (size_t)(srow + 128) * K1 + sq;
  const size_t gB0 = Bbase + (size_t)srow * K1 + sq;
  const size_t gB1 = Bbase + (size_t)(srow + 128) * K1 + sq;
  const int d0 = t * 16, d1 = 8192 + t * 16;   // LDS byte offsets

#define STAGE(sb, mat_, skh, skt) do {                                       \
    const int ktc_ = ((skt) < KT1 ? (skt) : (KT1 - 1));                      \
    const size_t ko_ = (size_t)ktc_ * 64 + (skh) * 32;                       \
    const bf16* p0_ = (mat_) ? (W + gB0 + ko_) : (A + gA0 + ko_);            \
    const bf16* p1_ = (mat_) ? (W + gB1 + ko_) : (A + gA1 + ko_);            \
    gload_lds16(p0_, (char*)&lds[sb][mat_][skh][0] + d0);                    \
    gload_lds16(p1_, (char*)&lds[sb][mat_][skh][0] + d1);                    \
  } while (0)

  floatx4 acc[8][4];
  const floatx4 z = {0.f, 0.f, 0.f, 0.f};
#pragma unroll
  for (int i = 0; i < 8; i++)
#pragma unroll
    for (int j = 0; j < 4; j++) acc[i][j] = z;

  // prologue: K-tile 0 (all 4 half-tiles) + K-tile 1 (kh0 halves)
  STAGE(0, 0, 0, 0); STAGE(0, 1, 0, 0); STAGE(0, 0, 1, 0); STAGE(0, 1, 1, 0);
  STAGE(1, 0, 0, 1); STAGE(1, 1, 0, 1);
  asm volatile("s_waitcnt vmcnt(4)" ::: "memory");   // K-tile 0 landed
  __builtin_amdgcn_s_barrier();

#define PHASE(cb, ks, mtg, sb, smat, skh, skt, VMW) do {                     \
    short8 af_[4], bf_[4];                                                   \
    _Pragma("unroll")                                                        \
    for (int mt = 0; mt < 4; ++mt) {                                         \
      const int row = wm + (mtg) * 64 + mt * 16 + r15;                       \
      af_[mt] = *(const short8*)((const char*)&lds[cb][0][ks][0] +           \
                                 row * 64 + ((quad ^ (row & 3)) << 4));      \
    }                                                                        \
    _Pragma("unroll")                                                        \
    for (int nt = 0; nt < 4; ++nt) {                                         \
      const int row = wn + nt * 16 + r15;                                    \
      bf_[nt] = *(const short8*)((const char*)&lds[cb][1][ks][0] +           \
                                 row * 64 + ((quad ^ (row & 3)) << 4));      \
    }                                                                        \
    STAGE(sb, smat, skh, skt);                                               \
    __builtin_amdgcn_sched_barrier(0);                                       \
    if (VMW) asm volatile("s_waitcnt vmcnt(4)" ::: "memory");                \
    __builtin_amdgcn_s_barrier();                                            \
    asm volatile("s_waitcnt lgkmcnt(0)" ::: "memory");                       \
    __builtin_amdgcn_sched_barrier(0);                                       \
    __builtin_amdgcn_s_setprio(1);                                           \
    _Pragma("unroll")                                                        \
    for (int mt = 0; mt < 4; ++mt)                                           \
      _Pragma("unroll")                                                      \
      for (int nt = 0; nt < 4; ++nt)                                         \
        acc[(mtg) * 4 + mt][nt] = __builtin_amdgcn_mfma_f32_16x16x32_bf16(   \
            af_[mt], bf_[nt], acc[(mtg) * 4 + mt][nt], 0, 0, 0);             \
    __builtin_amdgcn_s_setprio(0);                                           \
    __builtin_amdgcn_s_barrier();                                            \
  } while (0)

#pragma clang loop unroll(disable)
  for (int t2 = 0; t2 < KT1 / 2; ++t2) {
    const int n = 2 * t2;
    PHASE(0, 0, 0,  1, 0, 1, n + 1, 0);
    PHASE(0, 0, 1,  1, 1, 1, n + 1, 0);
    PHASE(0, 1, 0,  0, 0, 0, n + 2, 0);
    PHASE(0, 1, 1,  0, 1, 0, n + 2, 1);
    PHASE(1, 0, 0,  0, 0, 1, n + 2, 0);
    PHASE(1, 0, 1,  0, 1, 1, n + 2, 0);
    PHASE(1, 1, 0,  1, 0, 0, n + 3, 0);
    PHASE(1, 1, 1,  1, 1, 0, n + 3, 1);
  }
#undef PHASE
#undef STAGE

  // epilogue: bias + fast tanh, dual-write f32 (output) and bf16 (GEMM2 input)
  const int gcol0 = blockIdx.y * 256 + wn;
  float bv[4];
#pragma unroll
  for (int nt = 0; nt < 4; ++nt) bv[nt] = bias[gcol0 + nt * 16 + r15];
  const size_t grow0 = (size_t)blockIdx.x * 256 + wm;
#pragma unroll
  for (int mt = 0; mt < 8; ++mt) {
#pragma unroll
    for (int i = 0; i < 4; ++i) {
      const size_t gr = grow0 + mt * 16 + quad * 4 + i;
      const size_t rb = gr * (size_t)N1;
#pragma unroll
      for (int nt = 0; nt < 4; ++nt) {
        const int gc = gcol0 + nt * 16 + r15;
        float v = fast_tanh(acc[mt][nt][i] + bv[nt]);
        hf32[rb + gc] = v;
        hb16[rb + gc] = __float2bfloat16(v);
      }
    }
  }
}

// ---------------- GEMM2: out += h_new @ W_h2o^T (split-K=2) -------------
__global__ __launch_bounds__(256) void gemm2_out(
    const bf16* __restrict__ A, const bf16* __restrict__ W,
    float* __restrict__ out) {
  __shared__ bf16 As[32 * 64];    //  4 KB
  __shared__ bf16 Bs[256 * 64];   // 32 KB
  const int t    = threadIdx.x;
  const int lane = t & 63;
  const int wave = t >> 6;
  const int quad = lane >> 4;
  const int r15  = lane & 15;
  const int srow = t >> 3;   // 0..31
  const int sc   = t & 7;

  const int mrow0 = blockIdx.x * 32;
  const int kbase = blockIdx.y * (K2 / 2);   // 0 or 1024

  floatx4 acc[2][4];
  const floatx4 z = {0.f, 0.f, 0.f, 0.f};
#pragma unroll
  for (int i = 0; i < 2; i++)
#pragma unroll
    for (int j = 0; j < 4; j++) acc[i][j] = z;

  for (int kt = 0; kt < 16; ++kt) {
    const int k0 = kbase + kt * 64;
    __syncthreads();
    {  // A tile: 32 rows x 64 cols = one 16B issue per thread
      int row = srow;
      int gc  = k0 + ((sc ^ (row & 7)) << 3);
      gload_lds16(A + (size_t)(mrow0 + row) * K2 + gc, (char*)As + t * 16);
    }
#pragma unroll
    for (int it = 0; it < 8; ++it) {  // W tile: 256 rows x 64 cols
      int row = it * 32 + srow;
      int gc  = k0 + ((sc ^ (row & 7)) << 3);
      gload_lds16(W + (size_t)row * K2 + gc,
                  (char*)Bs + it * 4096 + t * 16);
    }
    __syncthreads();
#pragma unroll
    for (int ks = 0; ks < 2; ++ks) {
      short8 af[2], bfr[4];
      const int kq = ks * 4 + quad;
#pragma unroll
      for (int mt = 0; mt < 2; ++mt) {
        int row = mt * 16 + r15;
        af[mt] = *(const short8*)((const char*)As + row * 128 +
                                  ((kq ^ (row & 7)) << 4));
      }
#pragma unroll
      for (int nt = 0; nt < 4; ++nt) {
        int row = wave * 64 + nt * 16 + r15;
        bfr[nt] = *(const short8*)((const char*)Bs + row * 128 +
                                   ((kq ^ (row & 7)) << 4));
      }
#pragma unroll
      for (int mt = 0; mt < 2; ++mt)
#pragma unroll
        for (int nt = 0; nt < 4; ++nt)
          acc[mt][nt] = __builtin_amdgcn_mfma_f32_16x16x32_bf16(
              af[mt], bfr[nt], acc[mt][nt], 0, 0, 0);
    }
  }

  const int gcol0 = wave * 64;
#pragma unroll
  for (int mt = 0; mt < 2; ++mt) {
#pragma unroll
    for (int i = 0; i < 4; ++i) {
      size_t gr = (size_t)mrow0 + mt * 16 + quad * 4 + i;
      size_t rb = gr * (size_t)N2;
#pragma unroll
      for (int nt = 0; nt < 4; ++nt) {
        int gc = gcol0 + nt * 16 + r15;
        unsafeAtomicAdd(&out[rb + gc], acc[mt][nt][i]);
      }
    }
  }
}

extern "C" void kernel_launch(void* const* d_in, const int* in_sizes, int n_in,
                              void* d_out, int out_size, void* d_ws,
                              size_t ws_size, hipStream_t stream) {
  const float* x     = (const float*)d_in[0];  // [8192, 256]
  const float* h     = (const float*)d_in[1];  // [8192, 2048]
  const float* W_i2h = (const float*)d_in[2];  // [2048, 2304]
  const float* b_i2h = (const float*)d_in[3];  // [2048]
  const float* W_h2o = (const float*)d_in[4];  // [256, 2048]
  const float* b_h2o = (const float*)d_in[5];  // [256]

  float* out       = (float*)d_out;                    // [8192, 256]
  float* hnew_f32  = out + (size_t)BATCH * N2;         // [8192, 2048]

  bf16* comb   = (bf16*)d_ws;                          // 8192*2304
  bf16* Wi2h_b = comb + (size_t)BATCH * K1;            // 2048*2304
  bf16* Wh2o_b = Wi2h_b + (size_t)N1 * K1;             // 256*2048
  bf16* hnew_b = Wh2o_b + (size_t)N2 * K2;             // 8192*2048

  // seed out with bias (before gemm2's atomic accumulation; stream-ordered)
  bias_init<<<(BATCH * N2 / 4) / 256, 256, 0, stream>>>(b_h2o, out);

  // fused converters
  prep<<<(SEG0 + SEG1 + SEG2) / 256, 256, 0, stream>>>(
      x, h, W_i2h, W_h2o, comb, Wi2h_b, Wh2o_b);

  // GEMM1: 256x256 tiles, grid 32 x 8 = 256 blocks (1 per CU)
  gemm1_tanh<<<dim3(BATCH / 256, N1 / 256), 512, 0, stream>>>(
      comb, Wi2h_b, b_i2h, hnew_f32, hnew_b);

  // GEMM2: grid 256 x 2 (M-tiles x K-splits), atomic accumulate
  gemm2_out<<<dim3(BATCH / 32, 2), 256, 0, stream>>>(hnew_b, Wh2o_b, out);
}

// Round 2
// 259.987 us; speedup vs baseline: 1.0714x; 1.0257x over previous
//
#include <hip/hip_runtime.h>
#include <hip/hip_bf16.h>
#include <cstdint>

using bf16 = __hip_bfloat16;
typedef __attribute__((ext_vector_type(8))) short short8;
typedef __attribute__((ext_vector_type(4))) float floatx4;

// Problem constants
static constexpr int BATCH = 8192;
static constexpr int K1    = 2304;   // OBS + NH
static constexpr int N1    = 2048;   // NH
static constexpr int K2    = 2048;   // NH
static constexpr int N2    = 256;    // 2*LAT
static constexpr int KT1   = K1 / 64;  // 36 K-tiles of 64

__device__ __forceinline__ void gload_lds16(const void* g, void* l) {
  __builtin_amdgcn_global_load_lds(
      (const __attribute__((address_space(1))) void*)g,
      (__attribute__((address_space(3))) void*)l, 16, 0, 0);
}

// tanh(x) = 1 - 2/(1+e^{2x}); exp2-based, saturates to +/-1, err ~1e-6
__device__ __forceinline__ float fast_tanh(float x) {
  float e = __builtin_amdgcn_exp2f(x * 2.8853900817779268f);  // 2*log2(e)
  return 1.0f - 2.0f * __builtin_amdgcn_rcpf(e + 1.0f);
}

__device__ __forceinline__ short8 cvt8(const float* src) {
  float4 a = ((const float4*)src)[0];
  float4 b = ((const float4*)src)[1];
  union { short8 v; bf16 e[8]; } u;
  u.e[0] = __float2bfloat16(a.x); u.e[1] = __float2bfloat16(a.y);
  u.e[2] = __float2bfloat16(a.z); u.e[3] = __float2bfloat16(a.w);
  u.e[4] = __float2bfloat16(b.x); u.e[5] = __float2bfloat16(b.y);
  u.e[6] = __float2bfloat16(b.z); u.e[7] = __float2bfloat16(b.w);
  return u.v;
}

// ---------------- fused prep: cat(x,h)->bf16, W_i2h->bf16, W_h2o->bf16 ----
static constexpr int SEG0 = BATCH * (K1 / 8);          // 2,359,296
static constexpr int SEG1 = N1 * K1 / 8;               //   589,824
static constexpr int SEG2 = N2 * K2 / 8;               //    65,536
__global__ __launch_bounds__(256) void prep(
    const float* __restrict__ x, const float* __restrict__ h,
    const float* __restrict__ W1, const float* __restrict__ W2,
    bf16* __restrict__ comb, bf16* __restrict__ W1b, bf16* __restrict__ W2b) {
  int i = blockIdx.x * 256 + threadIdx.x;
  if (i < SEG0) {
    int row  = i / 288;
    int slot = i - row * 288;
    const float* src = (slot < 32) ? (x + (size_t)row * 256 + slot * 8)
                                   : (h + (size_t)row * 2048 + (slot - 32) * 8);
    *(short8*)(comb + (size_t)row * 2304 + slot * 8) = cvt8(src);
  } else if (i < SEG0 + SEG1) {
    int j = i - SEG0;
    *(short8*)(W1b + (size_t)j * 8) = cvt8(W1 + (size_t)j * 8);
  } else {
    int j = i - (SEG0 + SEG1);
    *(short8*)(W2b + (size_t)j * 8) = cvt8(W2 + (size_t)j * 8);
  }
}

// out = bias broadcast (seed for gemm2's split-K atomic accumulation)
__global__ __launch_bounds__(256) void bias_init(
    const float* __restrict__ bias, float* __restrict__ out) {
  int i = blockIdx.x * 256 + threadIdx.x;   // BATCH*64 threads, float4 each
  float4 b = ((const float4*)bias)[i & 63];
  ((float4*)out)[i] = b;
}

// ---------------- GEMM1: h_new = tanh(A @ W^T + bias) ----------------
// 256x256 tile, BK=64, 8 waves (2M x 4N), 128x64 per wave, 16x16x32 MFMA.
// 8-phase schedule. LDS [buf][A/B][khalf][256 rows x 32 bf16].
//
// LDS rows are 64 B (= 16 banks), so the bank index of (row, slot) is
// (row&1)*16 + slot*4 (mod 32).  Swizzle f(r) = (r>>1)&3 makes the
// combined index (r&1)*4 + (quad ^ f(r)) bijective over each 8-row group:
// a 16-lane column read touches all 32 banks twice (2-way = free).
// Round-1's f(r) = r&3 left rows {r, r+4} on identical banks -> 4-way
// conflict (9.4M SQ_LDS_BANK_CONFLICT, LDS-read-bound, MfmaUtil 26%).
//
// B fragments are read once per K-half and reused across the two mtg
// phases (held in 16 VGPRs over one barrier): 24 ds_read_b128 per wave
// per K-tile (16 A + 8 B) = the minimum.
//
// Stage schedule (iteration t, n = 2t; buf0 holds even K-tiles):
//   P0: buf1.A.kh1 <- n+1   P1: buf1.B.kh1 <- n+1
//   P2: buf0.A.kh0 <- n+2   P3: buf0.B.kh0 <- n+2  [vmcnt(4)]
//   P4: buf0.A.kh1 <- n+2   P5: buf0.B.kh1 <- n+2
//   P6: buf1.A.kh0 <- n+3   P7: buf1.B.kh0 <- n+3  [vmcnt(4)]
__global__ __launch_bounds__(512, 2) void gemm1_tanh(
    const bf16* __restrict__ A, const bf16* __restrict__ W,
    const float* __restrict__ bias,
    float* __restrict__ hf32, bf16* __restrict__ hb16) {
  __shared__ bf16 lds[2][2][2][8192];   // 128 KiB total
  const int t    = threadIdx.x;         // 0..511
  const int lane = t & 63;
  const int wave = t >> 6;              // 0..7
  const int wm   = (wave >> 2) * 128;   // 0 or 128
  const int wn   = (wave & 3) * 64;     // 0,64,128,192
  const int quad = lane >> 4;
  const int r15  = lane & 15;

  // staging: thread covers row r = j*128 + (t>>2), 16B slot s = t&3,
  // pre-swizzled global col so LDS dest stays linear (dest = j*8192 + t*16).
  const int srow  = t >> 2;             // 0..127
  const int sslot = t & 3;
  const int sq    = (sslot ^ ((srow >> 1) & 3)) * 8;  // elem offset in K-half

  const size_t Abase = (size_t)blockIdx.x * 256 * K1;
  const size_t Bbase = (size_t)blockIdx.y * 256 * K1;
  const size_t gA0 = Abase + (size_t)srow * K1 + sq;
  const size_t gA1 = Abase + (size_t)(srow + 128) * K1 + sq;
  const size_t gB0 = Bbase + (size_t)srow * K1 + sq;
  const size_t gB1 = Bbase + (size_t)(srow + 128) * K1 + sq;
  const int d0 = t * 16, d1 = 8192 + t * 16;   // LDS byte offsets

#define STAGE(sb, mat_, skh, skt) do {                                       \
    const int ktc_ = ((skt) < KT1 ? (skt) : (KT1 - 1));                      \
    const size_t ko_ = (size_t)ktc_ * 64 + (skh) * 32;                       \
    const bf16* p0_ = (mat_) ? (W + gB0 + ko_) : (A + gA0 + ko_);            \
    const bf16* p1_ = (mat_) ? (W + gB1 + ko_) : (A + gA1 + ko_);            \
    gload_lds16(p0_, (char*)&lds[sb][mat_][skh][0] + d0);                    \
    gload_lds16(p1_, (char*)&lds[sb][mat_][skh][0] + d1);                    \
  } while (0)

  floatx4 acc[8][4];
  const floatx4 z = {0.f, 0.f, 0.f, 0.f};
#pragma unroll
  for (int i = 0; i < 8; i++)
#pragma unroll
    for (int j = 0; j < 4; j++) acc[i][j] = z;

  // prologue: K-tile 0 (all 4 half-tiles) + K-tile 1 (kh0 halves)
  STAGE(0, 0, 0, 0); STAGE(0, 1, 0, 0); STAGE(0, 0, 1, 0); STAGE(0, 1, 1, 0);
  STAGE(1, 0, 0, 1); STAGE(1, 1, 0, 1);
  asm volatile("s_waitcnt vmcnt(4)" ::: "memory");   // K-tile 0 landed
  __builtin_amdgcn_s_barrier();

  short8 bf_[4];   // B fragments persist across the mtg-pair of phases

#define PHASE(cb, ks, mtg, LOADB, sb, smat, skh, skt, VMW) do {              \
    short8 af_[4];                                                           \
    _Pragma("unroll")                                                        \
    for (int mt = 0; mt < 4; ++mt) {                                         \
      const int row = wm + (mtg) * 64 + mt * 16 + r15;                       \
      af_[mt] = *(const short8*)((const char*)&lds[cb][0][ks][0] +           \
                                 row * 64 + ((quad ^ ((row >> 1) & 3)) << 4));\
    }                                                                        \
    if (LOADB) {                                                             \
      _Pragma("unroll")                                                      \
      for (int nt = 0; nt < 4; ++nt) {                                       \
        const int row = wn + nt * 16 + r15;                                  \
        bf_[nt] = *(const short8*)((const char*)&lds[cb][1][ks][0] +         \
                                   row * 64 + ((quad ^ ((row >> 1) & 3)) << 4));\
      }                                                                      \
    }                                                                        \
    STAGE(sb, smat, skh, skt);                                               \
    __builtin_amdgcn_sched_barrier(0);                                       \
    if (VMW) asm volatile("s_waitcnt vmcnt(4)" ::: "memory");                \
    __builtin_amdgcn_s_barrier();                                            \
    asm volatile("s_waitcnt lgkmcnt(0)" ::: "memory");                       \
    __builtin_amdgcn_sched_barrier(0);                                       \
    __builtin_amdgcn_s_setprio(1);                                           \
    _Pragma("unroll")                                                        \
    for (int mt = 0; mt < 4; ++mt)                                           \
      _Pragma("unroll")                                                      \
      for (int nt = 0; nt < 4; ++nt)                                         \
        acc[(mtg) * 4 + mt][nt] = __builtin_amdgcn_mfma_f32_16x16x32_bf16(   \
            af_[mt], bf_[nt], acc[(mtg) * 4 + mt][nt], 0, 0, 0);             \
    __builtin_amdgcn_s_setprio(0);                                           \
    __builtin_amdgcn_s_barrier();                                            \
  } while (0)

#pragma clang loop unroll(disable)
  for (int t2 = 0; t2 < KT1 / 2; ++t2) {
    const int n = 2 * t2;
    PHASE(0, 0, 0, 1,  1, 0, 1, n + 1, 0);
    PHASE(0, 0, 1, 0,  1, 1, 1, n + 1, 0);
    PHASE(0, 1, 0, 1,  0, 0, 0, n + 2, 0);
    PHASE(0, 1, 1, 0,  0, 1, 0, n + 2, 1);
    PHASE(1, 0, 0, 1,  0, 0, 1, n + 2, 0);
    PHASE(1, 0, 1, 0,  0, 1, 1, n + 2, 0);
    PHASE(1, 1, 0, 1,  1, 0, 0, n + 3, 0);
    PHASE(1, 1, 1, 0,  1, 1, 0, n + 3, 1);
  }
#undef PHASE
#undef STAGE

  // epilogue: bias + fast tanh, dual-write f32 (output) and bf16 (GEMM2 input)
  const int gcol0 = blockIdx.y * 256 + wn;
  float bv[4];
#pragma unroll
  for (int nt = 0; nt < 4; ++nt) bv[nt] = bias[gcol0 + nt * 16 + r15];
  const size_t grow0 = (size_t)blockIdx.x * 256 + wm;
#pragma unroll
  for (int mt = 0; mt < 8; ++mt) {
#pragma unroll
    for (int i = 0; i < 4; ++i) {
      const size_t gr = grow0 + mt * 16 + quad * 4 + i;
      const size_t rb = gr * (size_t)N1;
#pragma unroll
      for (int nt = 0; nt < 4; ++nt) {
        const int gc = gcol0 + nt * 16 + r15;
        float v = fast_tanh(acc[mt][nt][i] + bv[nt]);
        hf32[rb + gc] = v;
        hb16[rb + gc] = __float2bfloat16(v);
      }
    }
  }
}

// ---------------- GEMM2: out += h_new @ W_h2o^T (split-K=2) -------------
__global__ __launch_bounds__(256) void gemm2_out(
    const bf16* __restrict__ A, const bf16* __restrict__ W,
    float* __restrict__ out) {
  __shared__ bf16 As[32 * 64];    //  4 KB
  __shared__ bf16 Bs[256 * 64];   // 32 KB
  const int t    = threadIdx.x;
  const int lane = t & 63;
  const int wave = t >> 6;
  const int quad = lane >> 4;
  const int r15  = lane & 15;
  const int srow = t >> 3;   // 0..31
  const int sc   = t & 7;

  const int mrow0 = blockIdx.x * 32;
  const int kbase = blockIdx.y * (K2 / 2);   // 0 or 1024

  floatx4 acc[2][4];
  const floatx4 z = {0.f, 0.f, 0.f, 0.f};
#pragma unroll
  for (int i = 0; i < 2; i++)
#pragma unroll
    for (int j = 0; j < 4; j++) acc[i][j] = z;

  for (int kt = 0; kt < 16; ++kt) {
    const int k0 = kbase + kt * 64;
    __syncthreads();
    {  // A tile: 32 rows x 64 cols = one 16B issue per thread
      int row = srow;
      int gc  = k0 + ((sc ^ (row & 7)) << 3);
      gload_lds16(A + (size_t)(mrow0 + row) * K2 + gc, (char*)As + t * 16);
    }
#pragma unroll
    for (int it = 0; it < 8; ++it) {  // W tile: 256 rows x 64 cols
      int row = it * 32 + srow;
      int gc  = k0 + ((sc ^ (row & 7)) << 3);
      gload_lds16(W + (size_t)row * K2 + gc,
                  (char*)Bs + it * 4096 + t * 16);
    }
    __syncthreads();
#pragma unroll
    for (int ks = 0; ks < 2; ++ks) {
      short8 af[2], bfr[4];
      const int kq = ks * 4 + quad;
#pragma unroll
      for (int mt = 0; mt < 2; ++mt) {
        int row = mt * 16 + r15;
        af[mt] = *(const short8*)((const char*)As + row * 128 +
                                  ((kq ^ (row & 7)) << 4));
      }
#pragma unroll
      for (int nt = 0; nt < 4; ++nt) {
        int row = wave * 64 + nt * 16 + r15;
        bfr[nt] = *(const short8*)((const char*)Bs + row * 128 +
                                   ((kq ^ (row & 7)) << 4));
      }
#pragma unroll
      for (int mt = 0; mt < 2; ++mt)
#pragma unroll
        for (int nt = 0; nt < 4; ++nt)
          acc[mt][nt] = __builtin_amdgcn_mfma_f32_16x16x32_bf16(
              af[mt], bfr[nt], acc[mt][nt], 0, 0, 0);
    }
  }

  const int gcol0 = wave * 64;
#pragma unroll
  for (int mt = 0; mt < 2; ++mt) {
#pragma unroll
    for (int i = 0; i < 4; ++i) {
      size_t gr = (size_t)mrow0 + mt * 16 + quad * 4 + i;
      size_t rb = gr * (size_t)N2;
#pragma unroll
      for (int nt = 0; nt < 4; ++nt) {
        int gc = gcol0 + nt * 16 + r15;
        unsafeAtomicAdd(&out[rb + gc], acc[mt][nt][i]);
      }
    }
  }
}

extern "C" void kernel_launch(void* const* d_in, const int* in_sizes, int n_in,
                              void* d_out, int out_size, void* d_ws,
                              size_t ws_size, hipStream_t stream) {
  const float* x     = (const float*)d_in[0];  // [8192, 256]
  const float* h     = (const float*)d_in[1];  // [8192, 2048]
  const float* W_i2h = (const float*)d_in[2];  // [2048, 2304]
  const float* b_i2h = (const float*)d_in[3];  // [2048]
  const float* W_h2o = (const float*)d_in[4];  // [256, 2048]
  const float* b_h2o = (const float*)d_in[5];  // [256]

  float* out       = (float*)d_out;                    // [8192, 256]
  float* hnew_f32  = out + (size_t)BATCH * N2;         // [8192, 2048]

  bf16* comb   = (bf16*)d_ws;                          // 8192*2304
  bf16* Wi2h_b = comb + (size_t)BATCH * K1;            // 2048*2304
  bf16* Wh2o_b = Wi2h_b + (size_t)N1 * K1;             // 256*2048
  bf16* hnew_b = Wh2o_b + (size_t)N2 * K2;             // 8192*2048

  // seed out with bias (before gemm2's atomic accumulation; stream-ordered)
  bias_init<<<(BATCH * N2 / 4) / 256, 256, 0, stream>>>(b_h2o, out);

  // fused converters
  prep<<<(SEG0 + SEG1 + SEG2) / 256, 256, 0, stream>>>(
      x, h, W_i2h, W_h2o, comb, Wi2h_b, Wh2o_b);

  // GEMM1: 256x256 tiles, grid 32 x 8 = 256 blocks (1 per CU)
  gemm1_tanh<<<dim3(BATCH / 256, N1 / 256), 512, 0, stream>>>(
      comb, Wi2h_b, b_i2h, hnew_f32, hnew_b);

  // GEMM2: grid 256 x 2 (M-tiles x K-splits), atomic accumulate
  gemm2_out<<<dim3(BATCH / 32, 2), 256, 0, stream>>>(hnew_b, Wh2o_b, out);
}